// Round 7
// baseline (193.646 us; speedup 1.0000x reference)
//
#include <hip/hip_runtime.h>

typedef __attribute__((ext_vector_type(8))) short bf16x8;
typedef __attribute__((ext_vector_type(4))) float f32x4;

#define SZQKV 12582912  // B*N*C = one (q|k|v) output block, elements

__device__ __forceinline__ unsigned short f2bf(float f) {
    unsigned int u = __float_as_uint(f);
    unsigned int r = (u + 0x7FFFu + ((u >> 16) & 1u)) >> 16;
    return (unsigned short)r;
}

#define GLDS16(g, l) __builtin_amdgcn_global_load_lds( \
    (const __attribute__((address_space(1))) unsigned int*)(g), \
    (__attribute__((address_space(3))) unsigned int*)(l), 16, 0, 0)

// ---------------- cast f32 -> bf16 into workspace ----------------
__global__ void cast_all(const float* __restrict__ x,
                         const float* __restrict__ wqkv,
                         const float* __restrict__ wproj,
                         unsigned short* __restrict__ dst) {
    const int T1 = 12582912;       // x
    const int T2 = T1 + 1769472;   // + w_qkv
    const int T3 = T2 + 589824;    // + w_proj
    int stride = gridDim.x * blockDim.x * 4;
    for (int base = (blockIdx.x * blockDim.x + threadIdx.x) * 4; base < T3; base += stride) {
        const float* src; int off;
        if (base < T1)      { src = x;     off = base; }
        else if (base < T2) { src = wqkv;  off = base - T1; }
        else                { src = wproj; off = base - T2; }
        float4 v = *(const float4*)(src + off);
        ushort4 o;
        o.x = f2bf(v.x); o.y = f2bf(v.y); o.z = f2bf(v.z); o.w = f2bf(v.w);
        *(ushort4*)(dst + base) = o;
    }
}

// ---- 256x128 GEMM, BK=32, 4 waves (2m x 2n), 128x64 per wave, 3 blocks/CU ----
// A: [M][768] bf16. Bw: [Nw][768] bf16 (B^T). K = 768 = 24 K-tiles of 32.
// LDS: tile = A 256x32 (16KB) + B 128x32 (8KB) = 24KB; double-buffered = 48KB
//   -> 3 blocks/CU (144KB of 160KB), 12 waves/CU for cross-block latency hiding.
// Swizzle: 64B rows, 16B chunk pc; logical chunk = pc ^ (row&3). Frag reads land
//   uniformly 8 lanes per bank-quad = the b128 minimum (0 extra conflict cycles).
// Sync (R4-proven ordering): STAGE(kt+1) [6 loads]; vmcnt(6) [own tile kt landed];
//   barrier [all waves' tile kt landed]; compute; lgkmcnt(0); barrier [buf release].
template <int MODE>
__global__ __launch_bounds__(256, 3) void gemm4(const unsigned short* __restrict__ A,
                                                const unsigned short* __restrict__ Bw,
                                                const float* __restrict__ bias,
                                                float* __restrict__ dout,
                                                int nby) {
    __shared__ unsigned char lds8[49152];
    const int t = threadIdx.x;
    const int lane = t & 63;
    const int w = t >> 6;
    const int wm = w >> 1, wn = w & 1;   // 2m x 2n waves, 128x64 per wave

    // bijective XCD chunk swizzle (grid % 8 == 0)
    const int cpx = gridDim.x >> 3;
    const int orig = blockIdx.x;
    const int wgid = (orig & 7) * cpx + (orig >> 3);
    const int bx = wgid / nby, by = wgid - bx * nby;
    const int m0 = bx * 256, n0 = by * 128;

    const unsigned char* Ab = (const unsigned char*)A;
    const unsigned char* Bb = (const unsigned char*)Bw;

    // staging: slot s = g*256 + t -> row = g*64 + (t>>2), phys chunk pc = t&3;
    // global source chunk = pc ^ (row&3)  (row&3 == (t>>2)&3), LDS dst linear s*16.
    const int srow = t >> 2;
    const int sc = ((t & 3) ^ (srow & 3)) << 4;
    const size_t aBase = (size_t)(m0 + srow) * 1536 + sc;   // + g*98304 + kt*64
    const size_t bBase = (size_t)(n0 + srow) * 1536 + sc;
    const int ldst = t * 16;

    // fragment reads: row stride 64B; row&3 == lane&3 for all frags
    const int rA = wm * 128 + (lane & 15);
    const int rB = wn * 64 + (lane & 15);
    const int xt = (((lane >> 4)) ^ (lane & 3)) << 4;

    f32x4 acc[8][4] = {};

#define STAGE(kt, bsel) do { \
    unsigned char* db_ = lds8 + (bsel) * 24576; \
    const size_t ko_ = (size_t)(kt) * 64; \
    GLDS16(Ab + aBase + ko_,          db_ + ldst); \
    GLDS16(Ab + aBase + ko_ + 98304,  db_ + ldst + 4096); \
    GLDS16(Ab + aBase + ko_ + 196608, db_ + ldst + 8192); \
    GLDS16(Ab + aBase + ko_ + 294912, db_ + ldst + 12288); \
    GLDS16(Bb + bBase + ko_,          db_ + 16384 + ldst); \
    GLDS16(Bb + bBase + ko_ + 98304,  db_ + 16384 + ldst + 4096); \
} while (0)

#define LDA4(mb_) do { \
    _Pragma("unroll") \
    for (int mi = 0; mi < 4; ++mi) \
        av[mi] = *(const bf16x8*)(bufA + (rA + (mb_) + mi * 16) * 64 + xt); \
} while (0)

#define LDB4() do { \
    _Pragma("unroll") \
    for (int ni = 0; ni < 4; ++ni) \
        bv[ni] = *(const bf16x8*)(bufB + (rB + ni * 16) * 64 + xt); \
} while (0)

#define MM(rbase_) do { \
    __builtin_amdgcn_s_setprio(1); \
    _Pragma("unroll") \
    for (int mi = 0; mi < 4; ++mi) \
    _Pragma("unroll") \
    for (int ni = 0; ni < 4; ++ni) \
        acc[(rbase_) + mi][ni] = __builtin_amdgcn_mfma_f32_16x16x32_bf16(av[mi], bv[ni], acc[(rbase_) + mi][ni], 0, 0, 0); \
    __builtin_amdgcn_s_setprio(0); \
} while (0)

    STAGE(0, 0);
    for (int kt = 0; kt < 24; ++kt) {
        if (kt < 23) {
            STAGE(kt + 1, (kt + 1) & 1);
            asm volatile("s_waitcnt vmcnt(6)" ::: "memory");  // own tile-kt landed
        } else {
            asm volatile("s_waitcnt vmcnt(0)" ::: "memory");
        }
        __builtin_amdgcn_s_barrier();   // publish tile kt
        asm volatile("" ::: "memory");
        const unsigned char* bufA = lds8 + (kt & 1) * 24576;
        const unsigned char* bufB = bufA + 16384;
        bf16x8 av[4], bv[4];
        LDA4(0); LDB4(); MM(0);
        LDA4(64); MM(4);
        asm volatile("s_waitcnt lgkmcnt(0)" ::: "memory");
        __builtin_amdgcn_s_barrier();   // release buffer
        asm volatile("" ::: "memory");
    }
#undef STAGE
#undef LDA4
#undef LDB4
#undef MM

    const int ccol = lane & 15;
    const int hi4 = (lane >> 4) * 4;
    float* ldsf = (float*)lds8;
    if (MODE == 0) {
        // 4 sweeps of 32(o) x 256(n) f32 (32KB): stage transposed, store 1KB rows
        const int bidx = m0 >> 12;
        const int n_base = m0 & 4095;
#pragma unroll
        for (int s = 0; s < 4; ++s) {
            if (wn == (s >> 1)) {
#pragma unroll
                for (int mi = 0; mi < 8; ++mi)
#pragma unroll
                    for (int j = 0; j < 2; ++j) {
                        int ni = (s & 1) * 2 + j;
                        int o2 = j * 16 + ccol;                    // 0..31
                        int nl = wm * 128 + mi * 16 + hi4;         // 0..255
                        *(f32x4*)&ldsf[o2 * 256 + (nl ^ ((o2 & 7) << 2))] = acc[mi][ni];
                    }
            }
            asm volatile("s_waitcnt lgkmcnt(0)" ::: "memory");
            __builtin_amdgcn_s_barrier();
            asm volatile("" ::: "memory");
#pragma unroll
            for (int it = 0; it < 8; ++it) {
                int row = w * 8 + it;                              // 0..31
                int o = n0 + s * 32 + row;                         // col in [0,2304)
                int sel = o / 768;
                int rem = o - sel * 768;
                f32x4 v = *(const f32x4*)&ldsf[row * 256 + ((lane * 4) ^ ((row & 7) << 2))];
                float* dst = dout + (size_t)(3 - sel) * SZQKV
                           + ((size_t)((rem >> 8) * 4 + bidx) * 256 + (rem & 255)) * 4096
                           + n_base + lane * 4;
                *(f32x4*)dst = v;
            }
            if (s < 3) {
                asm volatile("s_waitcnt lgkmcnt(0)" ::: "memory");
                __builtin_amdgcn_s_barrier();
                asm volatile("" ::: "memory");
            }
        }
    } else {
        // 4 sweeps of 64(m) x 128(o) f32 (32KB): stage, add bias, 512B-contig stores
#pragma unroll
        for (int s = 0; s < 4; ++s) {
            if (wm == (s >> 1)) {
#pragma unroll
                for (int mj = 0; mj < 4; ++mj) {
                    int mi = (s & 1) * 4 + mj;
#pragma unroll
                    for (int ni = 0; ni < 4; ++ni) {
                        int o = wn * 64 + ni * 16 + ccol;          // 0..127
                        int m2b = mj * 16 + hi4;                   // 0..63
#pragma unroll
                        for (int r = 0; r < 4; ++r)
                            ldsf[(m2b + r) * 128 + (o ^ (((m2b + r) & 7) << 2))] = acc[mi][ni][r];
                    }
                }
            }
            asm volatile("s_waitcnt lgkmcnt(0)" ::: "memory");
            __builtin_amdgcn_s_barrier();
            asm volatile("" ::: "memory");
            float b0 = bias[n0 + lane * 2];
            float b1 = bias[n0 + lane * 2 + 1];
#pragma unroll
            for (int it = 0; it < 16; ++it) {
                int m2 = w * 16 + it;                              // 0..63
                float2 v = *(const float2*)&ldsf[m2 * 128 + ((lane * 2) ^ ((m2 & 7) << 2))];
                v.x += b0; v.y += b1;
                float* dst = dout + (size_t)(m0 + s * 64 + m2) * 768 + n0 + lane * 2;
                *(float2*)dst = v;
            }
            if (s < 3) {
                asm volatile("s_waitcnt lgkmcnt(0)" ::: "memory");
                __builtin_amdgcn_s_barrier();
                asm volatile("" ::: "memory");
            }
        }
    }
}

// ---------------- attention: read q/k/v f32 from d_out, write bf16 [b][n][c] ----------------
__global__ __launch_bounds__(256) void attn_kernel(const float* __restrict__ qkv,
                                                   unsigned short* __restrict__ attnbf) {
    const int chunk = blockIdx.x;  // 64 chunks of 64 n
    const int dil_i = blockIdx.y;  // 0..2
    const int b     = blockIdx.z;  // 0..3
    const int dil   = dil_i + 1;
    const int t  = threadIdx.x;
    const int h  = t >> 6;         // wave = head
    const int nl = t & 63;
    const int n  = chunk * 64 + nl;

    const size_t gb = (size_t)(dil_i * 4 + b) * 256 * 4096;
    const float* Q = qkv + (size_t)3 * SZQKV + gb;
    const float* K = qkv + (size_t)2 * SZQKV + gb;
    const float* V = qkv + (size_t)1 * SZQKV + gb;

    const int nm = n - dil, np = n + dil;
    const bool vm = (nm >= 0), vp = (np < 4096);
    const int nmc = vm ? nm : 0, npc = vp ? np : 4095;

    float s0 = 0.f, s1 = 0.f, s2 = 0.f;
    {
        const float* qrow = Q + (size_t)h * 64 * 4096;
        const float* krow = K + (size_t)h * 64 * 4096;
        for (int d = 0; d < 64; ++d) {
            float q = qrow[n];
            s0 += q * krow[nmc];
            s1 += q * krow[n];
            s2 += q * krow[npc];
            qrow += 4096; krow += 4096;
        }
    }
    s0 = vm ? s0 * 0.125f : 0.f;   // padded K-column -> exact 0 score (matches ref)
    s1 *= 0.125f;
    s2 = vp ? s2 * 0.125f : 0.f;
    float mx = fmaxf(0.f, fmaxf(s0, fmaxf(s1, s2)));
    float e0 = __expf(s0 - mx), e1 = __expf(s1 - mx), e2 = __expf(s2 - mx);
    // softmax over 9 slots: 6 structural zeros contribute 6*exp(-mx)
    float den = e0 + e1 + e2 + 6.f * __expf(-mx);
    float inv = 1.f / den;
    float p0 = vm ? e0 * inv : 0.f;
    float p1 = e1 * inv;
    float p2 = vp ? e2 * inv : 0.f;

    __shared__ unsigned short lout[256][65];  // [c'][n] bf16, padded row
    {
        const float* vrow = V + (size_t)h * 64 * 4096;
        for (int d = 0; d < 64; ++d) {
            float o = p0 * vrow[nmc] + p1 * vrow[n] + p2 * vrow[npc];
            lout[h * 64 + d][nl] = f2bf(o);
            vrow += 4096;
        }
    }
    __syncthreads();

    // write tile transposed: attnbf[(b*4096+n)*768 + dil_i*256 + c], c fastest
#pragma unroll
    for (int i = 0; i < 8; ++i) {
        int linear = i * 256 + t;   // 0..2047
        int nn   = linear >> 5;     // 0..63
        int cblk = linear & 31;     // 0..31 (8 channels each)
        union { unsigned short u[8]; f32x4 v; } tt;
#pragma unroll
        for (int j = 0; j < 8; ++j) tt.u[j] = lout[cblk * 8 + j][nn];
        unsigned short* dst = attnbf + (size_t)(b * 4096 + chunk * 64 + nn) * 768
                            + dil_i * 256 + cblk * 8;
        *(f32x4*)dst = tt.v;
    }
}

extern "C" void kernel_launch(void* const* d_in, const int* in_sizes, int n_in,
                              void* d_out, int out_size, void* d_ws, size_t ws_size,
                              hipStream_t stream) {
    const float* x     = (const float*)d_in[0];
    const float* wqkv  = (const float*)d_in[1];
    const float* wproj = (const float*)d_in[2];
    const float* bproj = (const float*)d_in[3];
    float* out = (float*)d_out;

    unsigned short* xbf     = (unsigned short*)d_ws;          // 12582912
    unsigned short* wqkvbf  = xbf + 12582912;                 // 1769472
    unsigned short* wprojbf = wqkvbf + 1769472;               // 589824
    unsigned short* attnbf  = wprojbf + 589824;               // 12582912

    cast_all<<<2048, 256, 0, stream>>>(x, wqkv, wproj, xbf);

    // qkv: M=16384 (64 m-tiles), Nw=2304 (18 n-tiles of 128) -> 1152 blocks (%8==0)
    gemm4<0><<<dim3(1152), 256, 0, stream>>>(xbf, wqkvbf, nullptr, out, 18);

    attn_kernel<<<dim3(64, 3, 4), 256, 0, stream>>>(out, attnbf);

    // proj: M=16384, Nw=768 (6 n-tiles) -> 384 blocks (%8==0)
    gemm4<1><<<dim3(384), 256, 0, stream>>>(attnbf, wprojbf, bproj, out, 6);
}

// Round 8
// 174.666 us; speedup vs baseline: 1.1087x; 1.1087x over previous
//
#include <hip/hip_runtime.h>

typedef __attribute__((ext_vector_type(8))) short bf16x8;
typedef __attribute__((ext_vector_type(4))) float f32x4;

#define SZQKV 12582912  // B*N*C = one (q|k|v) output block, elements

__device__ __forceinline__ unsigned short f2bf(float f) {
    unsigned int u = __float_as_uint(f);
    unsigned int r = (u + 0x7FFFu + ((u >> 16) & 1u)) >> 16;
    return (unsigned short)r;
}

#define GLDS16(g, l) __builtin_amdgcn_global_load_lds( \
    (const __attribute__((address_space(1))) unsigned int*)(g), \
    (__attribute__((address_space(3))) unsigned int*)(l), 16, 0, 0)

// ---------------- cast f32 -> bf16 into workspace ----------------
__global__ void cast_all(const float* __restrict__ x,
                         const float* __restrict__ wqkv,
                         const float* __restrict__ wproj,
                         unsigned short* __restrict__ dst) {
    const int T1 = 12582912;       // x
    const int T2 = T1 + 1769472;   // + w_qkv
    const int T3 = T2 + 589824;    // + w_proj
    int stride = gridDim.x * blockDim.x * 4;
    for (int base = (blockIdx.x * blockDim.x + threadIdx.x) * 4; base < T3; base += stride) {
        const float* src; int off;
        if (base < T1)      { src = x;     off = base; }
        else if (base < T2) { src = wqkv;  off = base - T1; }
        else                { src = wproj; off = base - T2; }
        float4 v = *(const float4*)(src + off);
        ushort4 o;
        o.x = f2bf(v.x); o.y = f2bf(v.y); o.z = f2bf(v.z); o.w = f2bf(v.w);
        *(ushort4*)(dst + base) = o;
    }
}

// ---------------- qkv GEMM: R2-verbatim 256x128 tile, BK=32, ring-3 dist-2, 2 blk/CU ----------------
// A: [M][768] bf16 row-major. Bw: [Nw][768] bf16 row-major (B^T input).
// LDS per buffer: A 256x32 bf16 = 16KB, B 128x32 bf16 = 8KB -> 24KB; x3 ring = 72KB.
// Swizzle: phys (row, pb) holds logical col-byte (pb ^ ((row&3)<<4)) -> wave64 ds_read_b128 bank-uniform.
template <int MODE>
__global__ __launch_bounds__(512, 2) void gemm_big(const unsigned short* __restrict__ A,
                                                   const unsigned short* __restrict__ Bw,
                                                   const float* __restrict__ bias,
                                                   float* __restrict__ dout,
                                                   int nby) {
    __shared__ unsigned char lds8[73728];
    const int t = threadIdx.x;
    const int lane = t & 63;
    const int w = t >> 6;
    const int wm = w >> 1, wn = w & 1;   // 4m x 2n waves, 64x64 tile each

    // bijective XCD chunk swizzle (grid sizes here are % 8 == 0)
    const int cpx = gridDim.x >> 3;
    const int orig = blockIdx.x;
    const int wgid = (orig & 7) * cpx + (orig >> 3);
    const int bx = wgid / nby, by = wgid - bx * nby;  // by fastest within chunk
    const int m0 = bx * 256;
    const int n0 = by * 128;

    const unsigned char* Ab = (const unsigned char*)A;
    const unsigned char* Bb = (const unsigned char*)Bw;

    // stage source offsets (bytes), inverse-swizzled so linear LDS dest = swizzled layout
    size_t aSrc0, aSrc1, bSrc;
    {
        int c0 = t, c1 = 512 + t;
        int r0 = c0 >> 2, p0 = (c0 & 3) << 4;
        int r1 = c1 >> 2, p1 = (c1 & 3) << 4;
        aSrc0 = (size_t)(m0 + r0) * 1536 + (p0 ^ ((r0 & 3) << 4));
        aSrc1 = (size_t)(m0 + r1) * 1536 + (p1 ^ ((r1 & 3) << 4));
        int rb = t >> 2, pb = (t & 3) << 4;
        bSrc  = (size_t)(n0 + rb) * 1536 + (pb ^ ((rb & 3) << 4));
    }

    // fragment read offsets (swizzled phys addr), loop-invariant
    int aOff[4], bOff[4];
#pragma unroll
    for (int mi = 0; mi < 4; ++mi) {
        int row = wm * 64 + mi * 16 + (lane & 15);
        aOff[mi] = row * 64 + ((((lane >> 4) << 4)) ^ ((row & 3) << 4));
    }
#pragma unroll
    for (int ni = 0; ni < 4; ++ni) {
        int row = wn * 64 + ni * 16 + (lane & 15);
        bOff[ni] = 16384 + row * 64 + ((((lane >> 4) << 4)) ^ ((row & 3) << 4));
    }

    f32x4 acc[4][4] = {};

#define STAGE(bi, kt) do { \
    unsigned char* dst_ = lds8 + (bi) * 24576; \
    GLDS16(Ab + aSrc0 + (size_t)(kt) * 64, dst_ + t * 16); \
    GLDS16(Ab + aSrc1 + (size_t)(kt) * 64, dst_ + 8192 + t * 16); \
    GLDS16(Bb + bSrc  + (size_t)(kt) * 64, dst_ + 16384 + t * 16); \
} while (0)

    STAGE(0, 0);
    STAGE(1, 1);
    int bi = 0;
    for (int kt = 0; kt < 24; ++kt) {
        if (kt < 22) {
            int si = bi + 2; if (si >= 3) si -= 3;
            STAGE(si, kt + 2);
            asm volatile("s_waitcnt vmcnt(6)" ::: "memory");   // tile kt's 3 loads done; 6 in flight
        } else if (kt == 22) {
            asm volatile("s_waitcnt vmcnt(3)" ::: "memory");
        } else {
            asm volatile("s_waitcnt vmcnt(0)" ::: "memory");
        }
        __builtin_amdgcn_s_barrier();
        asm volatile("" ::: "memory");
        const unsigned char* base = lds8 + bi * 24576;
        bf16x8 av[4], bv[4];
#pragma unroll
        for (int mi = 0; mi < 4; ++mi) av[mi] = *(const bf16x8*)(base + aOff[mi]);
#pragma unroll
        for (int ni = 0; ni < 4; ++ni) bv[ni] = *(const bf16x8*)(base + bOff[ni]);
#pragma unroll
        for (int mi = 0; mi < 4; ++mi)
#pragma unroll
            for (int ni = 0; ni < 4; ++ni)
                acc[mi][ni] = __builtin_amdgcn_mfma_f32_16x16x32_bf16(av[mi], bv[ni], acc[mi][ni], 0, 0, 0);
        // drain our ds_reads before the barrier: next iter's STAGE (other waves) overwrites this buffer
        asm volatile("s_waitcnt lgkmcnt(0)" ::: "memory");
        __builtin_amdgcn_s_barrier();
        asm volatile("" ::: "memory");
        ++bi; if (bi == 3) bi = 0;
    }
#undef STAGE

    const int crow = (lane >> 4) * 4;  // C row (+reg r)
    const int ccol = lane & 15;        // C col
    if (MODE == 0) {
        const int b = m0 >> 12;        // batch (m-tiles align with 4096 boundary)
        const int n_base = m0 & 4095;
#pragma unroll
        for (int mi = 0; mi < 4; ++mi) {
            int n = n_base + wm * 64 + mi * 16 + crow;  // 4 consecutive n (regs)
#pragma unroll
            for (int ni = 0; ni < 4; ++ni) {
                int o = n0 + wn * 64 + ni * 16 + ccol;  // column in [0,2304)
                int sel = o / 768;                      // 0=q 1=k 2=v
                int rem = o - sel * 768;                // dil*256 + c'
                float* dst = dout + (size_t)(3 - sel) * SZQKV
                           + ((size_t)((rem >> 8) * 4 + b) * 256 + (rem & 255)) * 4096 + n;
                *(f32x4*)dst = acc[mi][ni];
            }
        }
    } else {
#pragma unroll
        for (int mi = 0; mi < 4; ++mi) {
            int m = m0 + wm * 64 + mi * 16 + crow;
#pragma unroll
            for (int ni = 0; ni < 4; ++ni) {
                int o = n0 + wn * 64 + ni * 16 + ccol;
                float bb = bias[o];
#pragma unroll
                for (int r = 0; r < 4; ++r)
                    dout[(size_t)(m + r) * 768 + o] = acc[mi][ni][r] + bb;
            }
        }
    }
}

// ---------------- proj GEMM: 128x128 tile, BK=32, 4 waves, ring-3 dist-2, 3 blk/CU ----------------
// Full occupancy: grid 128x6 = 768 blocks = 256 CUs x 3 -> exactly 1.0 rounds.
// LDS: tile = A 128x32 (8KB) + B 128x32 (8KB) = 16KB; ring-3 = 48KB.
// Same swizzle + R2 sync protocol (STAGE(kt+2); vmcnt(8); barrier; compute; lgkm; barrier).
__global__ __launch_bounds__(256, 3) void gemm_proj128(const unsigned short* __restrict__ A,
                                                       const unsigned short* __restrict__ Bw,
                                                       const float* __restrict__ bias,
                                                       float* __restrict__ dout) {
    __shared__ unsigned char lds8[49152];
    const int t = threadIdx.x;
    const int lane = t & 63;
    const int w = t >> 6;                 // 0..3
    const int wm = w >> 1, wn = w & 1;    // 2m x 2n waves, 64x64 per wave

    const int cpx = gridDim.x >> 3;       // grid 768 % 8 == 0
    const int orig = blockIdx.x;
    const int wgid = (orig & 7) * cpx + (orig >> 3);
    const int bx = wgid / 6, by = wgid - bx * 6;
    const int m0 = bx * 128, n0 = by * 128;

    const unsigned char* Ab = (const unsigned char*)A;
    const unsigned char* Bb = (const unsigned char*)Bw;

    // staging: slot s = g*256+t -> row = g*64 + (t>>2), phys chunk = t&3;
    // global src chunk = (t&3) ^ (row&3); (row+64)&3 == row&3.
    const int srow = t >> 2;
    const int sc = ((t & 3) ^ (srow & 3)) << 4;
    const size_t aBase = (size_t)(m0 + srow) * 1536 + sc;
    const size_t bBase = (size_t)(n0 + srow) * 1536 + sc;
    const int ldst = t * 16;

    const int rA = wm * 64 + (lane & 15);
    const int rB = wn * 64 + (lane & 15);
    const int xt = (((lane >> 4)) ^ (lane & 3)) << 4;

    f32x4 acc[4][4] = {};

#define STAGE(kt, bi) do { \
    unsigned char* db_ = lds8 + (bi) * 16384; \
    const size_t ko_ = (size_t)(kt) * 64; \
    GLDS16(Ab + aBase + ko_,         db_ + ldst); \
    GLDS16(Ab + aBase + ko_ + 98304, db_ + ldst + 4096); \
    GLDS16(Bb + bBase + ko_,         db_ + 8192 + ldst); \
    GLDS16(Bb + bBase + ko_ + 98304, db_ + 8192 + ldst + 4096); \
} while (0)

    STAGE(0, 0);
    STAGE(1, 1);
    int bi = 0;
    for (int kt = 0; kt < 24; ++kt) {
        if (kt < 22) {
            int si = bi + 2; if (si >= 3) si -= 3;
            STAGE(kt + 2, si);
            asm volatile("s_waitcnt vmcnt(8)" ::: "memory");   // tile kt's 4 loads done
        } else if (kt == 22) {
            asm volatile("s_waitcnt vmcnt(4)" ::: "memory");
        } else {
            asm volatile("s_waitcnt vmcnt(0)" ::: "memory");
        }
        __builtin_amdgcn_s_barrier();
        asm volatile("" ::: "memory");
        const unsigned char* bufA = lds8 + bi * 16384;
        const unsigned char* bufB = bufA + 8192;
        bf16x8 av[4], bv[4];
#pragma unroll
        for (int mi = 0; mi < 4; ++mi)
            av[mi] = *(const bf16x8*)(bufA + (rA + mi * 16) * 64 + xt);
#pragma unroll
        for (int ni = 0; ni < 4; ++ni)
            bv[ni] = *(const bf16x8*)(bufB + (rB + ni * 16) * 64 + xt);
#pragma unroll
        for (int mi = 0; mi < 4; ++mi)
#pragma unroll
            for (int ni = 0; ni < 4; ++ni)
                acc[mi][ni] = __builtin_amdgcn_mfma_f32_16x16x32_bf16(av[mi], bv[ni], acc[mi][ni], 0, 0, 0);
        asm volatile("s_waitcnt lgkmcnt(0)" ::: "memory");
        __builtin_amdgcn_s_barrier();
        asm volatile("" ::: "memory");
        ++bi; if (bi == 3) bi = 0;
    }
#undef STAGE

    // epilogue: 2 sweeps of 64(m) x 128(o) f32 (32KB LDS), 512B-contiguous stores + bias
    float* ldsf = (float*)lds8;
    const int ccol = lane & 15;
    const int hi4 = (lane >> 4) * 4;
#pragma unroll
    for (int s = 0; s < 2; ++s) {
        if (wm == s) {
#pragma unroll
            for (int mi = 0; mi < 4; ++mi)
#pragma unroll
                for (int ni = 0; ni < 4; ++ni) {
                    int o = wn * 64 + ni * 16 + ccol;          // 0..127
                    int m2b = mi * 16 + hi4;                   // 0..63 (+r)
#pragma unroll
                    for (int r = 0; r < 4; ++r)
                        ldsf[(m2b + r) * 128 + (o ^ (((m2b + r) & 7) << 2))] = acc[mi][ni][r];
                }
        }
        asm volatile("s_waitcnt lgkmcnt(0)" ::: "memory");
        __builtin_amdgcn_s_barrier();
        asm volatile("" ::: "memory");
#pragma unroll
        for (int it = 0; it < 8; ++it) {
            int idx = it * 256 + t;                            // 0..2047
            int row = idx >> 5;                                // 0..63
            int c4 = (idx & 31) * 4;                           // 0..124
            f32x4 v = *(const f32x4*)&ldsf[row * 128 + (c4 ^ ((row & 7) << 2))];
            f32x4 b4 = *(const f32x4*)(bias + n0 + c4);
            v = v + b4;
            float* dst = dout + (size_t)(m0 + s * 64 + row) * 768 + n0 + c4;
            *(f32x4*)dst = v;
        }
        if (s == 0) {
            __builtin_amdgcn_s_barrier();
            asm volatile("" ::: "memory");
        }
    }
}

// ---------------- attention: read q/k/v f32 from d_out, write bf16 [b][n][c] ----------------
__global__ __launch_bounds__(256) void attn_kernel(const float* __restrict__ qkv,
                                                   unsigned short* __restrict__ attnbf) {
    const int chunk = blockIdx.x;  // 64 chunks of 64 n
    const int dil_i = blockIdx.y;  // 0..2
    const int b     = blockIdx.z;  // 0..3
    const int dil   = dil_i + 1;
    const int t  = threadIdx.x;
    const int h  = t >> 6;         // wave = head
    const int nl = t & 63;
    const int n  = chunk * 64 + nl;

    const size_t gb = (size_t)(dil_i * 4 + b) * 256 * 4096;
    const float* Q = qkv + (size_t)3 * SZQKV + gb;
    const float* K = qkv + (size_t)2 * SZQKV + gb;
    const float* V = qkv + (size_t)1 * SZQKV + gb;

    const int nm = n - dil, np = n + dil;
    const bool vm = (nm >= 0), vp = (np < 4096);
    const int nmc = vm ? nm : 0, npc = vp ? np : 4095;

    float s0 = 0.f, s1 = 0.f, s2 = 0.f;
    {
        const float* qrow = Q + (size_t)h * 64 * 4096;
        const float* krow = K + (size_t)h * 64 * 4096;
        for (int d = 0; d < 64; ++d) {
            float q = qrow[n];
            s0 += q * krow[nmc];
            s1 += q * krow[n];
            s2 += q * krow[npc];
            qrow += 4096; krow += 4096;
        }
    }
    s0 = vm ? s0 * 0.125f : 0.f;   // padded K-column -> exact 0 score (matches ref)
    s1 *= 0.125f;
    s2 = vp ? s2 * 0.125f : 0.f;
    float mx = fmaxf(0.f, fmaxf(s0, fmaxf(s1, s2)));
    float e0 = __expf(s0 - mx), e1 = __expf(s1 - mx), e2 = __expf(s2 - mx);
    // softmax over 9 slots: 6 structural zeros contribute 6*exp(-mx)
    float den = e0 + e1 + e2 + 6.f * __expf(-mx);
    float inv = 1.f / den;
    float p0 = vm ? e0 * inv : 0.f;
    float p1 = e1 * inv;
    float p2 = vp ? e2 * inv : 0.f;

    __shared__ unsigned short lout[256][65];  // [c'][n] bf16, padded row
    {
        const float* vrow = V + (size_t)h * 64 * 4096;
        for (int d = 0; d < 64; ++d) {
            float o = p0 * vrow[nmc] + p1 * vrow[n] + p2 * vrow[npc];
            lout[h * 64 + d][nl] = f2bf(o);
            vrow += 4096;
        }
    }
    __syncthreads();

    // write tile transposed: attnbf[(b*4096+n)*768 + dil_i*256 + c], c fastest
#pragma unroll
    for (int i = 0; i < 8; ++i) {
        int linear = i * 256 + t;   // 0..2047
        int nn   = linear >> 5;     // 0..63
        int cblk = linear & 31;     // 0..31 (8 channels each)
        union { unsigned short u[8]; f32x4 v; } tt;
#pragma unroll
        for (int j = 0; j < 8; ++j) tt.u[j] = lout[cblk * 8 + j][nn];
        unsigned short* dst = attnbf + (size_t)(b * 4096 + chunk * 64 + nn) * 768
                            + dil_i * 256 + cblk * 8;
        *(f32x4*)dst = tt.v;
    }
}

extern "C" void kernel_launch(void* const* d_in, const int* in_sizes, int n_in,
                              void* d_out, int out_size, void* d_ws, size_t ws_size,
                              hipStream_t stream) {
    const float* x     = (const float*)d_in[0];
    const float* wqkv  = (const float*)d_in[1];
    const float* wproj = (const float*)d_in[2];
    const float* bproj = (const float*)d_in[3];
    float* out = (float*)d_out;

    unsigned short* xbf     = (unsigned short*)d_ws;          // 12582912
    unsigned short* wqkvbf  = xbf + 12582912;                 // 1769472
    unsigned short* wprojbf = wqkvbf + 1769472;               // 589824
    unsigned short* attnbf  = wprojbf + 589824;               // 12582912

    cast_all<<<2048, 256, 0, stream>>>(x, wqkv, wproj, xbf);

    // qkv: M=16384, Nw=2304 -> grid 64 x 18 = 1152 (%8==0), R2-verbatim config
    gemm_big<0><<<dim3(64 * 18), 512, 0, stream>>>(xbf, wqkvbf, nullptr, out, 18);

    attn_kernel<<<dim3(64, 3, 4), 256, 0, stream>>>(out, attnbf);

    // proj: M=16384 (128 m-tiles), Nw=768 (6 n-tiles) -> 768 blocks, 3 blk/CU, 1.0 rounds
    gemm_proj128<<<dim3(768), 256, 0, stream>>>(attnbf, wprojbf, bproj, out);
}

// Round 9
// 174.276 us; speedup vs baseline: 1.1111x; 1.0022x over previous
//
#include <hip/hip_runtime.h>

typedef __attribute__((ext_vector_type(8))) short bf16x8;
typedef __attribute__((ext_vector_type(4))) float f32x4;

#define SZQKV 12582912  // B*N*C = one (q|k|v) output block, elements

__device__ __forceinline__ unsigned short f2bf(float f) {
    unsigned int u = __float_as_uint(f);
    unsigned int r = (u + 0x7FFFu + ((u >> 16) & 1u)) >> 16;
    return (unsigned short)r;
}

#define GLDS16(g, l) __builtin_amdgcn_global_load_lds( \
    (const __attribute__((address_space(1))) unsigned int*)(g), \
    (__attribute__((address_space(3))) unsigned int*)(l), 16, 0, 0)

// ---------------- cast f32 -> bf16 into workspace ----------------
__global__ void cast_all(const float* __restrict__ x,
                         const float* __restrict__ wqkv,
                         const float* __restrict__ wproj,
                         unsigned short* __restrict__ dst) {
    const int T1 = 12582912;       // x
    const int T2 = T1 + 1769472;   // + w_qkv
    const int T3 = T2 + 589824;    // + w_proj
    int stride = gridDim.x * blockDim.x * 4;
    for (int base = (blockIdx.x * blockDim.x + threadIdx.x) * 4; base < T3; base += stride) {
        const float* src; int off;
        if (base < T1)      { src = x;     off = base; }
        else if (base < T2) { src = wqkv;  off = base - T1; }
        else                { src = wproj; off = base - T2; }
        float4 v = *(const float4*)(src + off);
        ushort4 o;
        o.x = f2bf(v.x); o.y = f2bf(v.y); o.z = f2bf(v.z); o.w = f2bf(v.w);
        *(ushort4*)(dst + base) = o;
    }
}

// ---- qkv GEMM: 256x128 tile, BK=32, 4 waves (2m x 2n -> 128x64/wave, 384 B/MFMA),
//      ring-3 distance-2 prefetch (72KB LDS), 2 blk/CU. Sync = R2-proven protocol. ----
// A: [M][768] bf16. Bw: [2304][768] bf16 (B^T). 24 K-tiles of 32.
// Swizzle: 64B rows, 16B chunk pc; logical chunk = pc ^ (row&3) -> conflict-free b128.
// Per iter: STAGE(kt+2) [6 loads]; vmcnt(12) [own tile kt landed, 2 stages in flight];
//   barrier; ds_read + 32 MFMA (bv reused across both m-halves); lgkmcnt(0); barrier.
__global__ __launch_bounds__(256, 2) void gemm_qkv(const unsigned short* __restrict__ A,
                                                   const unsigned short* __restrict__ Bw,
                                                   float* __restrict__ dout) {
    __shared__ unsigned char lds8[73728];
    const int t = threadIdx.x;
    const int lane = t & 63;
    const int w = t >> 6;
    const int wm = w >> 1, wn = w & 1;   // 2m x 2n waves, 128x64 per wave

    // bijective XCD chunk swizzle (grid 1152 % 8 == 0)
    const int cpx = gridDim.x >> 3;
    const int orig = blockIdx.x;
    const int wgid = (orig & 7) * cpx + (orig >> 3);
    const int bx = wgid / 18, by = wgid - bx * 18;
    const int m0 = bx * 256, n0 = by * 128;

    const unsigned char* Ab = (const unsigned char*)A;
    const unsigned char* Bb = (const unsigned char*)Bw;

    // staging: slot s = g*256 + t -> row = g*64 + (t>>2), phys chunk pc = t&3;
    // global source chunk = pc ^ (row&3)  (row&3 == (t>>2)&3), LDS dst linear s*16.
    const int srow = t >> 2;
    const int sc = ((t & 3) ^ (srow & 3)) << 4;
    const size_t aBase = (size_t)(m0 + srow) * 1536 + sc;   // + g*98304 + kt*64
    const size_t bBase = (size_t)(n0 + srow) * 1536 + sc;
    const int ldst = t * 16;

    // fragment reads: row stride 64B; row&3 == lane&3 for all frags
    const int rA = wm * 128 + (lane & 15);
    const int rB = wn * 64 + (lane & 15);
    const int xt = (((lane >> 4)) ^ (lane & 3)) << 4;

    f32x4 acc[8][4] = {};

#define STAGE(kt, bi) do { \
    unsigned char* db_ = lds8 + (bi) * 24576; \
    const size_t ko_ = (size_t)(kt) * 64; \
    GLDS16(Ab + aBase + ko_,          db_ + ldst); \
    GLDS16(Ab + aBase + ko_ + 98304,  db_ + ldst + 4096); \
    GLDS16(Ab + aBase + ko_ + 196608, db_ + ldst + 8192); \
    GLDS16(Ab + aBase + ko_ + 294912, db_ + ldst + 12288); \
    GLDS16(Bb + bBase + ko_,          db_ + 16384 + ldst); \
    GLDS16(Bb + bBase + ko_ + 98304,  db_ + 16384 + ldst + 4096); \
} while (0)

#define LDA4(mb_) do { \
    _Pragma("unroll") \
    for (int mi = 0; mi < 4; ++mi) \
        av[mi] = *(const bf16x8*)(bufA + (rA + (mb_) + mi * 16) * 64 + xt); \
} while (0)

#define MM(rbase_) do { \
    __builtin_amdgcn_s_setprio(1); \
    _Pragma("unroll") \
    for (int mi = 0; mi < 4; ++mi) \
    _Pragma("unroll") \
    for (int ni = 0; ni < 4; ++ni) \
        acc[(rbase_) + mi][ni] = __builtin_amdgcn_mfma_f32_16x16x32_bf16(av[mi], bv[ni], acc[(rbase_) + mi][ni], 0, 0, 0); \
    __builtin_amdgcn_s_setprio(0); \
} while (0)

    STAGE(0, 0);
    STAGE(1, 1);
    int bi = 0;
    for (int kt = 0; kt < 24; ++kt) {
        if (kt < 22) {
            int si = bi + 2; if (si >= 3) si -= 3;
            STAGE(kt + 2, si);
            asm volatile("s_waitcnt vmcnt(12)" ::: "memory");  // own tile-kt landed; 2 stages in flight
        } else if (kt == 22) {
            asm volatile("s_waitcnt vmcnt(6)" ::: "memory");
        } else {
            asm volatile("s_waitcnt vmcnt(0)" ::: "memory");
        }
        __builtin_amdgcn_s_barrier();   // publish tile kt
        asm volatile("" ::: "memory");
        const unsigned char* bufA = lds8 + bi * 24576;
        const unsigned char* bufB = bufA + 16384;
        bf16x8 av[4], bv[4];
#pragma unroll
        for (int ni = 0; ni < 4; ++ni)
            bv[ni] = *(const bf16x8*)(bufB + (rB + ni * 16) * 64 + xt);
        LDA4(0);  MM(0);
        LDA4(64); MM(4);
        asm volatile("s_waitcnt lgkmcnt(0)" ::: "memory");
        __builtin_amdgcn_s_barrier();   // release buffer
        asm volatile("" ::: "memory");
        ++bi; if (bi == 3) bi = 0;
    }
#undef STAGE
#undef LDA4
#undef MM

    // direct-scatter epilogue (R2 style): f32x4 = 4 consecutive n per store
    const int crow = (lane >> 4) * 4;
    const int ccol = lane & 15;
    const int b = m0 >> 12;
    const int n_base = m0 & 4095;
#pragma unroll
    for (int mi = 0; mi < 8; ++mi) {
        int n = n_base + wm * 128 + mi * 16 + crow;
#pragma unroll
        for (int ni = 0; ni < 4; ++ni) {
            int o = n0 + wn * 64 + ni * 16 + ccol;  // column in [0,2304)
            int sel = o / 768;                      // 0=q 1=k 2=v
            int rem = o - sel * 768;                // dil*256 + c'
            float* dst = dout + (size_t)(3 - sel) * SZQKV
                       + ((size_t)((rem >> 8) * 4 + b) * 256 + (rem & 255)) * 4096 + n;
            *(f32x4*)dst = acc[mi][ni];
        }
    }
}

// ---------------- proj GEMM: 128x128 tile, BK=32, 4 waves, ring-3 dist-2, 3 blk/CU ----------------
__global__ __launch_bounds__(256, 3) void gemm_proj128(const unsigned short* __restrict__ A,
                                                       const unsigned short* __restrict__ Bw,
                                                       const float* __restrict__ bias,
                                                       float* __restrict__ dout) {
    __shared__ unsigned char lds8[49152];
    const int t = threadIdx.x;
    const int lane = t & 63;
    const int w = t >> 6;                 // 0..3
    const int wm = w >> 1, wn = w & 1;    // 2m x 2n waves, 64x64 per wave

    const int cpx = gridDim.x >> 3;       // grid 768 % 8 == 0
    const int orig = blockIdx.x;
    const int wgid = (orig & 7) * cpx + (orig >> 3);
    const int bx = wgid / 6, by = wgid - bx * 6;
    const int m0 = bx * 128, n0 = by * 128;

    const unsigned char* Ab = (const unsigned char*)A;
    const unsigned char* Bb = (const unsigned char*)Bw;

    const int srow = t >> 2;
    const int sc = ((t & 3) ^ (srow & 3)) << 4;
    const size_t aBase = (size_t)(m0 + srow) * 1536 + sc;
    const size_t bBase = (size_t)(n0 + srow) * 1536 + sc;
    const int ldst = t * 16;

    const int rA = wm * 64 + (lane & 15);
    const int rB = wn * 64 + (lane & 15);
    const int xt = (((lane >> 4)) ^ (lane & 3)) << 4;

    f32x4 acc[4][4] = {};

#define STAGE(kt, bi) do { \
    unsigned char* db_ = lds8 + (bi) * 16384; \
    const size_t ko_ = (size_t)(kt) * 64; \
    GLDS16(Ab + aBase + ko_,         db_ + ldst); \
    GLDS16(Ab + aBase + ko_ + 98304, db_ + ldst + 4096); \
    GLDS16(Bb + bBase + ko_,         db_ + 8192 + ldst); \
    GLDS16(Bb + bBase + ko_ + 98304, db_ + 8192 + ldst + 4096); \
} while (0)

    STAGE(0, 0);
    STAGE(1, 1);
    int bi = 0;
    for (int kt = 0; kt < 24; ++kt) {
        if (kt < 22) {
            int si = bi + 2; if (si >= 3) si -= 3;
            STAGE(kt + 2, si);
            asm volatile("s_waitcnt vmcnt(8)" ::: "memory");   // tile kt's 4 loads done
        } else if (kt == 22) {
            asm volatile("s_waitcnt vmcnt(4)" ::: "memory");
        } else {
            asm volatile("s_waitcnt vmcnt(0)" ::: "memory");
        }
        __builtin_amdgcn_s_barrier();
        asm volatile("" ::: "memory");
        const unsigned char* bufA = lds8 + bi * 16384;
        const unsigned char* bufB = bufA + 8192;
        bf16x8 av[4], bv[4];
#pragma unroll
        for (int mi = 0; mi < 4; ++mi)
            av[mi] = *(const bf16x8*)(bufA + (rA + mi * 16) * 64 + xt);
#pragma unroll
        for (int ni = 0; ni < 4; ++ni)
            bv[ni] = *(const bf16x8*)(bufB + (rB + ni * 16) * 64 + xt);
#pragma unroll
        for (int mi = 0; mi < 4; ++mi)
#pragma unroll
            for (int ni = 0; ni < 4; ++ni)
                acc[mi][ni] = __builtin_amdgcn_mfma_f32_16x16x32_bf16(av[mi], bv[ni], acc[mi][ni], 0, 0, 0);
        asm volatile("s_waitcnt lgkmcnt(0)" ::: "memory");
        __builtin_amdgcn_s_barrier();
        asm volatile("" ::: "memory");
        ++bi; if (bi == 3) bi = 0;
    }
#undef STAGE

    // epilogue: 2 sweeps of 64(m) x 128(o) f32 (32KB LDS), 512B-contiguous stores + bias
    float* ldsf = (float*)lds8;
    const int ccol = lane & 15;
    const int hi4 = (lane >> 4) * 4;
#pragma unroll
    for (int s = 0; s < 2; ++s) {
        if (wm == s) {
#pragma unroll
            for (int mi = 0; mi < 4; ++mi)
#pragma unroll
                for (int ni = 0; ni < 4; ++ni) {
                    int o = wn * 64 + ni * 16 + ccol;          // 0..127
                    int m2b = mi * 16 + hi4;                   // 0..63 (+r)
#pragma unroll
                    for (int r = 0; r < 4; ++r)
                        ldsf[(m2b + r) * 128 + (o ^ (((m2b + r) & 7) << 2))] = acc[mi][ni][r];
                }
        }
        asm volatile("s_waitcnt lgkmcnt(0)" ::: "memory");
        __builtin_amdgcn_s_barrier();
        asm volatile("" ::: "memory");
#pragma unroll
        for (int it = 0; it < 8; ++it) {
            int idx = it * 256 + t;                            // 0..2047
            int row = idx >> 5;                                // 0..63
            int c4 = (idx & 31) * 4;                           // 0..124
            f32x4 v = *(const f32x4*)&ldsf[row * 128 + (c4 ^ ((row & 7) << 2))];
            f32x4 b4 = *(const f32x4*)(bias + n0 + c4);
            v = v + b4;
            float* dst = dout + (size_t)(m0 + s * 64 + row) * 768 + n0 + c4;
            *(f32x4*)dst = v;
        }
        if (s == 0) {
            __builtin_amdgcn_s_barrier();
            asm volatile("" ::: "memory");
        }
    }
}

// ---------------- attention: read q/k/v f32 from d_out, write bf16 [b][n][c] ----------------
__global__ __launch_bounds__(256) void attn_kernel(const float* __restrict__ qkv,
                                                   unsigned short* __restrict__ attnbf) {
    const int chunk = blockIdx.x;  // 64 chunks of 64 n
    const int dil_i = blockIdx.y;  // 0..2
    const int b     = blockIdx.z;  // 0..3
    const int dil   = dil_i + 1;
    const int t  = threadIdx.x;
    const int h  = t >> 6;         // wave = head
    const int nl = t & 63;
    const int n  = chunk * 64 + nl;

    const size_t gb = (size_t)(dil_i * 4 + b) * 256 * 4096;
    const float* Q = qkv + (size_t)3 * SZQKV + gb;
    const float* K = qkv + (size_t)2 * SZQKV + gb;
    const float* V = qkv + (size_t)1 * SZQKV + gb;

    const int nm = n - dil, np = n + dil;
    const bool vm = (nm >= 0), vp = (np < 4096);
    const int nmc = vm ? nm : 0, npc = vp ? np : 4095;

    float s0 = 0.f, s1 = 0.f, s2 = 0.f;
    {
        const float* qrow = Q + (size_t)h * 64 * 4096;
        const float* krow = K + (size_t)h * 64 * 4096;
        for (int d = 0; d < 64; ++d) {
            float q = qrow[n];
            s0 += q * krow[nmc];
            s1 += q * krow[n];
            s2 += q * krow[npc];
            qrow += 4096; krow += 4096;
        }
    }
    s0 = vm ? s0 * 0.125f : 0.f;   // padded K-column -> exact 0 score (matches ref)
    s1 *= 0.125f;
    s2 = vp ? s2 * 0.125f : 0.f;
    float mx = fmaxf(0.f, fmaxf(s0, fmaxf(s1, s2)));
    float e0 = __expf(s0 - mx), e1 = __expf(s1 - mx), e2 = __expf(s2 - mx);
    // softmax over 9 slots: 6 structural zeros contribute 6*exp(-mx)
    float den = e0 + e1 + e2 + 6.f * __expf(-mx);
    float inv = 1.f / den;
    float p0 = vm ? e0 * inv : 0.f;
    float p1 = e1 * inv;
    float p2 = vp ? e2 * inv : 0.f;

    __shared__ unsigned short lout[256][65];  // [c'][n] bf16, padded row
    {
        const float* vrow = V + (size_t)h * 64 * 4096;
        for (int d = 0; d < 64; ++d) {
            float o = p0 * vrow[nmc] + p1 * vrow[n] + p2 * vrow[npc];
            lout[h * 64 + d][nl] = f2bf(o);
            vrow += 4096;
        }
    }
    __syncthreads();

    // write tile transposed: attnbf[(b*4096+n)*768 + dil_i*256 + c], c fastest
#pragma unroll
    for (int i = 0; i < 8; ++i) {
        int linear = i * 256 + t;   // 0..2047
        int nn   = linear >> 5;     // 0..63
        int cblk = linear & 31;     // 0..31 (8 channels each)
        union { unsigned short u[8]; f32x4 v; } tt;
#pragma unroll
        for (int j = 0; j < 8; ++j) tt.u[j] = lout[cblk * 8 + j][nn];
        unsigned short* dst = attnbf + (size_t)(b * 4096 + chunk * 64 + nn) * 768
                            + dil_i * 256 + cblk * 8;
        *(f32x4*)dst = tt.v;
    }
}

extern "C" void kernel_launch(void* const* d_in, const int* in_sizes, int n_in,
                              void* d_out, int out_size, void* d_ws, size_t ws_size,
                              hipStream_t stream) {
    const float* x     = (const float*)d_in[0];
    const float* wqkv  = (const float*)d_in[1];
    const float* wproj = (const float*)d_in[2];
    const float* bproj = (const float*)d_in[3];
    float* out = (float*)d_out;

    unsigned short* xbf     = (unsigned short*)d_ws;          // 12582912
    unsigned short* wqkvbf  = xbf + 12582912;                 // 1769472
    unsigned short* wprojbf = wqkvbf + 1769472;               // 589824
    unsigned short* attnbf  = wprojbf + 589824;               // 12582912

    cast_all<<<2048, 256, 0, stream>>>(x, wqkv, wproj, xbf);

    // qkv: M=16384 (64 m-tiles of 256), Nw=2304 (18 n-tiles of 128) -> 1152 blocks (%8==0)
    gemm_qkv<<<dim3(1152), 256, 0, stream>>>(xbf, wqkvbf, out);

    attn_kernel<<<dim3(64, 3, 4), 256, 0, stream>>>(out, attnbf);

    // proj: M=16384 (128 m-tiles), Nw=768 (6 n-tiles) -> 768 blocks, 3 blk/CU, 1.0 rounds
    gemm_proj128<<<dim3(768), 256, 0, stream>>>(attnbf, wprojbf, bproj, out);
}